// Round 1
// baseline (118.433 us; speedup 1.0000x reference)
//
#include <hip/hip_runtime.h>
#include <math.h>

#define LAM 0.3f
#define EPS 1e-8f

constexpr int B = 32, T = 12, N = 5000, C = 8, E = 5000, M = 160000;
constexpr int F = 16;          // 2*C feature dim
constexpr int RH = B * F;      // 512 halves per node across ALL batches
constexpr int HR = 256;        // halves per node per batch-half (16 b x 16 f)
constexpr size_t HN = (size_t)N * HR; // halves per batch-half region

typedef _Float16 half8 __attribute__((ext_vector_type(8)));
typedef _Float16 half2v __attribute__((ext_vector_type(2)));

__device__ __forceinline__ float dot16(const half8& m, const half8& c, float p0) {
    float p = p0;
#if __has_builtin(__builtin_amdgcn_fdot2)
#pragma unroll
    for (int k = 0; k < 4; ++k) {
        half2v a = {m[2 * k], m[2 * k + 1]};
        half2v c2 = {c[2 * k], c[2 * k + 1]};
        p = __builtin_amdgcn_fdot2(a, c2, p, false);
    }
#else
#pragma unroll
    for (int k = 0; k < 8; ++k) p = fmaf((float)m[k], (float)c[k], p);
#endif
    return p;
}

__device__ __forceinline__ float clip01(float p) {
    return fminf(fmaxf(p, 0.0f), 1.0f);
}

// ---------------------------------------------------------------------------
// Kernel 1 (fused): blocks 0..624 -> 8 nodes x 32 batches (one (b,n)/thread).
// mean/std over T, unit-normalize, fp16, transpose via padded LDS, write out
// as ufeat[h][n][256] (h = b>>4): 2 x 4KB contiguous coalesced sweeps/block.
// Block 625 -> exclusive prefix scan of counts -> starts.   (UNCHANGED)
// ---------------------------------------------------------------------------
__global__ __launch_bounds__(256) void feat_scan_kernel(const float* __restrict__ x,
                                                        const float* __restrict__ counts,
                                                        _Float16* __restrict__ ufeat,
                                                        int* __restrict__ starts) {
    if (blockIdx.x == 625) {
        constexpr int PER = (E + 255) / 256; // 20
        __shared__ int tsum[256];
        int tid = threadIdx.x;
        int base = tid * PER;
        int local[PER];
        int s = 0;
#pragma unroll
        for (int k = 0; k < PER; ++k) {
            int e = base + k;
            int c = (e < E) ? (int)counts[e] : 0;
            local[k] = s;
            s += c;
        }
        tsum[tid] = s;
        __syncthreads();
        for (int off = 1; off < 256; off <<= 1) {
            int v = (tid >= off) ? tsum[tid - off] : 0;
            __syncthreads();
            tsum[tid] += v;
            __syncthreads();
        }
        int prefix = (tid == 0) ? 0 : tsum[tid - 1];
#pragma unroll
        for (int k = 0; k < PER; ++k) {
            int e = base + k;
            if (e < E) starts[e] = prefix + local[k];
        }
        return;
    }

    // ---- feat: 625 blocks x (8 nodes, 32 batches) ----
    int tid = threadIdx.x;
    int nb = blockIdx.x * 8;   // node base (625*8 = 5000 exact)
    int nl = tid & 7;          // node local
    int b  = tid >> 3;         // batch 0..31
    int n  = nb + nl;

    const float* p = x + ((size_t)b * T * N + n) * C;

    float s[8] = {0, 0, 0, 0, 0, 0, 0, 0};
    float q2[8] = {0, 0, 0, 0, 0, 0, 0, 0};
#pragma unroll
    for (int t = 0; t < T; ++t) {
        const float* pt = p + (size_t)t * N * C;
        float4 a = *(const float4*)(pt);
        float4 bq = *(const float4*)(pt + 4);
        float v[8] = {a.x, a.y, a.z, a.w, bq.x, bq.y, bq.z, bq.w};
#pragma unroll
        for (int c = 0; c < 8; ++c) {
            s[c] += v[c];
            q2[c] += v[c] * v[c];
        }
    }

    float u[16];
    float n2 = 0.0f;
#pragma unroll
    for (int c = 0; c < 8; ++c) {
        float mean = s[c] * (1.0f / T);
        float var = (q2[c] - s[c] * mean) * (1.0f / (T - 1));
        float sd = sqrtf(fmaxf(var, 0.0f));
        u[c] = mean;
        u[8 + c] = sd;
        n2 += mean * mean + sd * sd;
    }
    float scale = 1.0f / fmaxf(sqrtf(n2), EPS);

    // LDS transpose: sfeat[node][b*16+f], row padded +8 halves
    __shared__ _Float16 sfeat[8][RH + 8];
    half8 h0, h1;
#pragma unroll
    for (int c = 0; c < 8; ++c) h0[c] = (_Float16)(u[c] * scale);
#pragma unroll
    for (int c = 0; c < 8; ++c) h1[c] = (_Float16)(u[8 + c] * scale);
    *(half8*)&sfeat[nl][b * F + 0] = h0;
    *(half8*)&sfeat[nl][b * F + 8] = h1;
    __syncthreads();

    // coalesced write-out into [h][n][256]: per h, 8 rows x 512B = 4KB contiguous
#pragma unroll
    for (int h = 0; h < 2; ++h) {
        int nr = tid >> 5;           // row 0..7
        int off = tid & 31;          // 16B granule within 512B row
        half8 v = *(const half8*)&sfeat[nr][(h * 16 + (off >> 1)) * F + (off & 1) * 8];
        *(half8*)(ufeat + (size_t)h * HN + (size_t)(nb + nr) * HR + off * 8) = v;
    }
}

// ---------------------------------------------------------------------------
// Kernel 2: one wave per (edge, batch-half).  Block swizzle maps batch-half h
// to XCD group so each XCD's L2 serves one 2.56MB half.
// NEW (R8): member-index stream is wave-uniform -> fetch via readfirstlane-
// derived scalar loads (s_load, constant cache) instead of vector-load +
// ds_bpermute broadcast.  Inner loop: 16 SGPR indices per chunk, 8 independent
// global_load_dwordx4 in flight per half-wave-pair, zero LDS ops.
// ALL loop bounds remain wave-uniform (scalar cnt) -- per-half-wave divergent
// bounds fail reproducibly on HW (R6/R7, absmax 3.1e-2).  Tail uses clamped
// scalar loads + uniform scalar guards; odd member computed by both halves,
// counted only for hw==0 (R5-equivalent predication).
// ---------------------------------------------------------------------------
__global__ __launch_bounds__(256) void sim_kernel(const _Float16* __restrict__ ufeat,
                                                  const int* __restrict__ members,
                                                  const int* __restrict__ centers,
                                                  const int* __restrict__ starts,
                                                  const float* __restrict__ counts,
                                                  float* __restrict__ mean_sim) {
    int linear = blockIdx.x;                     // 0..2511 (padded)
    int h = (linear & 4) >> 2;                   // XCDs 0-3 -> h=0, 4-7 -> h=1
    int e4 = (linear >> 3) * 4 + (linear & 3);   // edge-quad 0..1255 (padded)
    if (e4 >= E / 4) return;
    int wid = __builtin_amdgcn_readfirstlane(threadIdx.x >> 6); // wave id, SGPR
    int e = e4 * 4 + wid;                        // uniform
    int lane = threadIdx.x & 63;
    int g32 = lane & 31;   // 16B granule within 512B row
    int hw = lane >> 5;    // half-wave id -> member parity

    int start = __builtin_amdgcn_readfirstlane(starts[e]);
    int cnt   = __builtin_amdgcn_readfirstlane((int)counts[e]);
    int ce    = __builtin_amdgcn_readfirstlane(centers[e]);
    float cntf = (float)cnt;

    const _Float16* base = ufeat + (size_t)h * HN;
    const half8 c8 = *(const half8*)(base + (size_t)ce * HR + g32 * 8);
    const char* cbase = (const char*)base + (size_t)g32 * 16; // per-lane base

    float acc = 0.0f;
    const int* sp = members + start;             // wave-uniform pointer

    int nfull = cnt >> 4;
    for (int cc = 0; cc < nfull; ++cc) {
        int sm[16];
#pragma unroll
        for (int k = 0; k < 16; ++k)
            sm[k] = __builtin_amdgcn_readfirstlane(sp[k]);   // -> s_load
        sp += 16;
#pragma unroll
        for (int k = 0; k < 8; ++k) {
            int offA = sm[2 * k] * 512;          // scalar shifts
            int offB = sm[2 * k + 1] * 512;
            int off = hw ? offB : offA;          // one cndmask
            half8 a = *(const half8*)(cbase + off);
            float p = dot16(a, c8, 0.0f);
            p += __shfl_xor(p, 1);               // quad-perm DPP
            acc += clip01(p);
        }
    }

    int rem = cnt & 15;
    if (rem) {
        int sm[16];
#pragma unroll
        for (int k = 0; k < 16; ++k) {
            int idx = (k < rem) ? k : (rem - 1); // clamp: never OOB past members[M]
            sm[k] = __builtin_amdgcn_readfirstlane(sp[idx]);
        }
#pragma unroll
        for (int k = 0; k < 8; ++k) {
            int j0 = 2 * k, j1 = 2 * k + 1;
            if (j0 < rem) {                      // uniform scalar guard
                bool pair = (j1 < rem);
                int offA = sm[j0] * 512;
                int offB = (pair ? sm[j1] : sm[j0]) * 512;
                int off = hw ? offB : offA;
                half8 a = *(const half8*)(cbase + off);
                float p = dot16(a, c8, 0.0f);
                p += __shfl_xor(p, 1);
                float v = clip01(p);
                acc += (pair || hw == 0) ? v : 0.0f; // odd member counted once
            }
        }
    }

    acc += __shfl_xor(acc, 32);      // combine the two member-parity halves
    if (lane < 32 && (g32 & 1) == 0) {
        int b = h * 16 + (g32 >> 1);
        mean_sim[(size_t)b * E + e] = acc / fmaxf(cntf, 1.0f);
    }
}

// ---------------------------------------------------------------------------
// Kernel 3: per-batch min/max over E then write W[e]*(1+LAM*norm).
// One 1024-thread block per b.   (UNCHANGED)
// ---------------------------------------------------------------------------
__global__ __launch_bounds__(1024) void norm_kernel(const float* __restrict__ mean_sim,
                                                    const float* __restrict__ W,
                                                    float* __restrict__ out) {
    int b = blockIdx.x;
    const float* row = mean_sim + (size_t)b * E;
    float mn = INFINITY, mx = -INFINITY;
    for (int e = threadIdx.x; e < E; e += 1024) {
        float v = row[e];
        mn = fminf(mn, v);
        mx = fmaxf(mx, v);
    }
#pragma unroll
    for (int off = 32; off > 0; off >>= 1) {
        mn = fminf(mn, __shfl_down(mn, off));
        mx = fmaxf(mx, __shfl_down(mx, off));
    }
    __shared__ float smn[16], smx[16];
    __shared__ float fmn, fmx;
    int w = threadIdx.x >> 6, lane = threadIdx.x & 63;
    if (lane == 0) { smn[w] = mn; smx[w] = mx; }
    __syncthreads();
    if (threadIdx.x == 0) {
        float a = INFINITY, c = -INFINITY;
        for (int i = 0; i < 16; ++i) {
            a = fminf(a, smn[i]);
            c = fmaxf(c, smx[i]);
        }
        fmn = a; fmx = c;
    }
    __syncthreads();
    float mnv = fmn;
    float inv = 1.0f / (fmx - mnv + EPS);
    for (int e = threadIdx.x; e < E; e += 1024) {
        out[(size_t)b * E + e] = W[e] * (1.0f + LAM * (row[e] - mnv) * inv);
    }
}

extern "C" void kernel_launch(void* const* d_in, const int* in_sizes, int n_in,
                              void* d_out, int out_size, void* d_ws, size_t ws_size,
                              hipStream_t stream) {
    const float* x_raw    = (const float*)d_in[0];
    const float* W        = (const float*)d_in[1];
    const int*   members  = (const int*)d_in[2];
    const int*   centers  = (const int*)d_in[3];
    const int*   edge_ids = (const int*)d_in[4]; (void)edge_ids;
    const float* counts   = (const float*)d_in[5];
    float* out = (float*)d_out;

    _Float16* ufeat   = (_Float16*)d_ws;                    // 2*N*256 halves = 5.12 MB
    float* mean_sim   = (float*)(ufeat + 2 * HN);           // B*E floats = 640 KB
    int*   starts     = (int*)(mean_sim + (size_t)B * E);   // E ints

    feat_scan_kernel<<<626, 256, 0, stream>>>(x_raw, counts, ufeat, starts);
    // 2512 = 314 groups of 8 blocks (4 x h=0, 4 x h=1); e4 padded, checked in-kernel
    sim_kernel<<<2512, 256, 0, stream>>>(ufeat, members, centers, starts,
                                         counts, mean_sim);
    norm_kernel<<<B, 1024, 0, stream>>>(mean_sim, W, out);
}